// Round 9
// baseline (20.649 us; speedup 1.0000x reference)
//
#include <hip/hip_runtime.h>
#include <hip/hip_bf16.h>

#define B_   16
#define NC_  1024
#define NQ_  128
#define D_   512
#define BM   16
#define BK   64
#define NKT  8        // K-tiles: 512/64

typedef __attribute__((ext_vector_type(8))) short bf16x8;
typedef __attribute__((ext_vector_type(4))) float f32x4;
typedef __attribute__((address_space(3))) char lds_char;
typedef const __attribute__((address_space(1))) char g_char;

// fp32 -> bf16 RTNE
__device__ __forceinline__ short f2bf(float x) {
    return __builtin_bit_cast(short, __float2bfloat16(x));
}

// Pre-kernel: qw[b][j][d] = bf16(q*w_cq + w_c); qterm[b][j] = q . w_q
__global__ __launch_bounds__(256) void prep_kernel(
    const float* __restrict__ q, const float* __restrict__ kern,
    short* __restrict__ qw, float* __restrict__ qterm)
{
    const int tid  = threadIdx.x;
    const int lane = tid & 63;
    const int row  = blockIdx.x * 4 + (tid >> 6);   // 0..2047 (b*128 + j)
    const int k0   = lane * 8;
    const float* qr = q + (size_t)row * D_;
    f32x4 a0 = *(const f32x4*)(qr + k0);
    f32x4 a1 = *(const f32x4*)(qr + k0 + 4);
    f32x4 g0 = *(const f32x4*)(kern + 2 * D_ + k0);      // w_cq
    f32x4 g1 = *(const f32x4*)(kern + 2 * D_ + k0 + 4);
    f32x4 w0 = *(const f32x4*)(kern + D_ + k0);          // w_q
    f32x4 w1 = *(const f32x4*)(kern + D_ + k0 + 4);
    f32x4 h0 = *(const f32x4*)(kern + k0);               // w_c
    f32x4 h1 = *(const f32x4*)(kern + k0 + 4);
    bf16x8 o;
    o[0] = f2bf(a0[0] * g0[0] + h0[0]); o[1] = f2bf(a0[1] * g0[1] + h0[1]);
    o[2] = f2bf(a0[2] * g0[2] + h0[2]); o[3] = f2bf(a0[3] * g0[3] + h0[3]);
    o[4] = f2bf(a1[0] * g1[0] + h1[0]); o[5] = f2bf(a1[1] * g1[1] + h1[1]);
    o[6] = f2bf(a1[2] * g1[2] + h1[2]); o[7] = f2bf(a1[3] * g1[3] + h1[3]);
    *(bf16x8*)(qw + (size_t)row * D_ + k0) = o;
    float s = a0[0]*w0[0] + a0[1]*w0[1] + a0[2]*w0[2] + a0[3]*w0[3]
            + a1[0]*w1[0] + a1[1]*w1[1] + a1[2]*w1[2] + a1[3]*w1[3];
    s += __shfl_xor(s, 1);  s += __shfl_xor(s, 2);  s += __shfl_xor(s, 4);
    s += __shfl_xor(s, 8);  s += __shfl_xor(s, 16); s += __shfl_xor(s, 32);
    if (lane == 0) qterm[row] = s;
}

// Main GEMM: out[b][i][j] = (c[b][i] . qw[b][j]) + qterm[b][j] + bias
// R8-verified 2-phase structure; R9 geometry: BM=16, LDS/buf = A fp32 [16][64] (4KB)
// + B bf16 [128][64] (16KB) = 20KB -> dbuf 40KB -> 4 blocks/CU. Grid 1024 (=4/CU).
// XCD-affinity decode: b = ((bid&7)<<1)|(bid>>9) -> each XCD serves 2 batches,
// so that batch's qw slice (2x128KB) stays hot in its private L2.
// Swizzle unchanged: byte_in_row ^= (row&7)<<4 (pre-swizzled global src, swz read).
__global__ __launch_bounds__(256, 4) void sim_kernel(
    const float* __restrict__ c, const short* __restrict__ qw,
    const float* __restrict__ qterm, const float* __restrict__ bias_p,
    float* __restrict__ out)
{
    __shared__ char lds[2][20480];

    const int bid  = blockIdx.x;
    const int b    = ((bid & 7) << 1) | (bid >> 9);  // XCD-affine batch (bijective)
    const int mt   = (bid >> 3) & 63;                // 64 M-tiles per batch
    const int tid  = threadIdx.x;
    const int lane = tid & 63;
    const int w    = tid >> 6;          // wave 0..3 -> N columns w*32..w*32+31
    const int rif  = lane & 15;
    const int kg   = lane >> 4;

    // --- staging source addresses (per lane), k-tile 0 ---
    // A: 4KB = 4 wave-chunks of 1KB, one per wave (ch = w); row = ch*4 + lane>>4 (256B rows)
    const char* asrc; int adst;
    {
        int r = w * 4 + (lane >> 4);
        int so = ((lane & 15) * 16) ^ ((r & 7) << 4);
        asrc = (const char*)c + ((size_t)(b * NC_ + mt * BM + r) * D_) * 4 + so;
        adst = w * 1024 + lane * 16;
    }
    // B: 16KB = 16 wave-chunks; ch = w*4+l covers j-rows ch*8..+7 (128B rows)
    const char* bsrc[4]; int bdst[4];
    #pragma unroll
    for (int l = 0; l < 4; ++l) {
        int ch = w * 4 + l;
        int j  = ch * 8 + (lane >> 3);
        int so = ((lane & 7) * 16) ^ ((j & 7) << 4);
        bsrc[l] = (const char*)qw + ((size_t)(b * NQ_ + j) * D_) * 2 + so;
        bdst[l] = 4096 + ch * 1024 + lane * 16;
    }

#define STAGE(BUF, KT)                                                            \
    do {                                                                          \
        lds_char* L_ = (lds_char*)&lds[(BUF)][0];                                 \
        __builtin_amdgcn_global_load_lds((g_char*)(asrc + (KT) * 256),            \
                                         (lds_char*)(L_ + adst), 16, 0, 0);       \
        __builtin_amdgcn_global_load_lds((g_char*)(bsrc[0] + (KT) * 128),         \
                                         (lds_char*)(L_ + bdst[0]), 16, 0, 0);    \
        __builtin_amdgcn_global_load_lds((g_char*)(bsrc[1] + (KT) * 128),         \
                                         (lds_char*)(L_ + bdst[1]), 16, 0, 0);    \
        __builtin_amdgcn_global_load_lds((g_char*)(bsrc[2] + (KT) * 128),         \
                                         (lds_char*)(L_ + bdst[2]), 16, 0, 0);    \
        __builtin_amdgcn_global_load_lds((g_char*)(bsrc[3] + (KT) * 128),         \
                                         (lds_char*)(L_ + bdst[3]), 16, 0, 0);    \
    } while (0)

    f32x4 acc[2] = {};

    STAGE(0, 0);
    asm volatile("s_waitcnt vmcnt(0)" ::: "memory");
    __syncthreads();

    int buf = 0;
    #pragma unroll 1
    for (int kt = 0; kt < NKT; ++kt) {
        if (kt + 1 < NKT) STAGE(buf ^ 1, kt + 1);

        const char* L = &lds[buf][0];
        #pragma unroll
        for (int kk = 0; kk < 2; ++kk) {
            // A-frag: row rif, fp32 -> bf16
            bf16x8 af;
            {
                int sw = (rif & 7) << 4;
                f32x4 v0 = *(const f32x4*)(L + rif * 256 + ((kk * 128 + kg * 32 +  0) ^ sw));
                f32x4 v1 = *(const f32x4*)(L + rif * 256 + ((kk * 128 + kg * 32 + 16) ^ sw));
                af[0] = f2bf(v0[0]); af[1] = f2bf(v0[1]); af[2] = f2bf(v0[2]); af[3] = f2bf(v0[3]);
                af[4] = f2bf(v1[0]); af[5] = f2bf(v1[1]); af[6] = f2bf(v1[2]); af[7] = f2bf(v1[3]);
            }
            #pragma unroll
            for (int nf = 0; nf < 2; ++nf) {
                int j = w * 32 + nf * 16 + rif;
                bf16x8 bfr = *(const bf16x8*)(L + 4096 + j * 128
                                              + ((kk * 64 + kg * 16) ^ ((j & 7) << 4)));
                acc[nf] = __builtin_amdgcn_mfma_f32_16x16x32_bf16(af, bfr, acc[nf], 0, 0, 0);
            }
        }

        asm volatile("s_waitcnt vmcnt(0)" ::: "memory");
        __syncthreads();
        buf ^= 1;
    }
#undef STAGE

    const float bias = *bias_p;
    #pragma unroll
    for (int nf = 0; nf < 2; ++nf) {
        const float qt = qterm[b * NQ_ + w * 32 + nf * 16 + rif] + bias;
        float* o = out + ((size_t)(b * NC_ + mt * BM + kg * 4)) * NQ_
                 + w * 32 + nf * 16 + rif;
        #pragma unroll
        for (int r = 0; r < 4; ++r)
            o[(size_t)r * NQ_] = acc[nf][r] + qt;
    }
}

extern "C" void kernel_launch(void* const* d_in, const int* in_sizes, int n_in,
                              void* d_out, int out_size, void* d_ws, size_t ws_size,
                              hipStream_t stream) {
    const float* c    = (const float*)d_in[0];
    const float* q    = (const float*)d_in[1];
    const float* kern = (const float*)d_in[2];
    const float* bias = (const float*)d_in[3];
    float* out = (float*)d_out;

    // ws layout: qw bf16 [2048][512] (2 MiB) | qterm f32 [2048]
    short* qw    = (short*)d_ws;
    float* qterm = (float*)((char*)d_ws + (size_t)2048 * 512 * 2);

    prep_kernel<<<512, 256, 0, stream>>>(q, kern, qw, qterm);
    sim_kernel<<<1024, 256, 0, stream>>>(c, qw, qterm, bias, out);  // 16 x 64 tiles, XCD-affine
}